// Round 9
// baseline (433.470 us; speedup 1.0000x reference)
//
#include <hip/hip_runtime.h>
#include <hip/hip_bf16.h>
#include <cstddef>

// MHAttention forward, MI355X/gfx950.
// Dtype contract (R0-R3): inputs fp32 (toks, W*, b*; masks int32), OUTPUT fp32.
// Internals: bf16 MFMA fragments, fp32 accumulation.
// R20 -> R21 post-mortem: R20 failed absmax (1.2e-2 ~ one stale tile in 32).
// Root cause: polluted hand-counted vmcnt stream -- ck f32x4[2][4] arrays
// passed by-reference through a lambda (rule-#20 alloca risk) + ~240 VGPR
// estimate => scratch VMEM ops corrupt the DMA FIFO count => vmcnt(16)
// releases before the tile lands. R21 keeps the de-convoy structure (1-wave
// blocks, zero barriers, swizzled global_load_lds staging) and makes the
// vmcnt stream provably clean: the ONLY loop VMEM = 16 DMAs/body.
// (a) masks as BITS: one u32/lane (mask_all) covers the batch row; per tile
//     two uniform v_readlane + bit-test/cndmask replace all ck float loads
//     (-64 VGPR, no in-loop mask VMEM). actq from readlane too.
// (b) no lambda, no ref-arrays: plain loop, runtime (t&1)*4096 buffer offset.
// (c) uniform s_waitcnt vmcnt(16)/body, exact by construction.

typedef __bf16 bf16_8 __attribute__((ext_vector_type(8)));
typedef float f32x4 __attribute__((ext_vector_type(4)));
typedef float f32x16 __attribute__((ext_vector_type(16)));
typedef short s16x4 __attribute__((ext_vector_type(4)));
typedef short s16x8 __attribute__((ext_vector_type(8)));
typedef unsigned int u32x4 __attribute__((ext_vector_type(4)));

#define HID 768
#define NHEADS 12
#define HD 64
#define BATCH 4
#define SEQ 2048
#define NEGBIG2 (-1.44269504e31f)  // -1e31 * log2e, exp2 -> 0
#define SCALE2 0.18033688f         // 0.125 * log2e

#define KVB 64           // keys per tile
#define NKT (SEQ / KVB)  // 32
#define STRQ 68          // Q slab row stride (padded, prologue only)
#define ASTR 72          // proj LDS row stride (elems)

static __device__ __forceinline__ f32x4 mfma16x16x32(bf16_8 a, bf16_8 b, f32x4 c) {
  return __builtin_amdgcn_mfma_f32_16x16x32_bf16(a, b, c, 0, 0, 0);
}
static __device__ __forceinline__ f32x16 mfma32x32x16(bf16_8 a, bf16_8 b, f32x16 c) {
  return __builtin_amdgcn_mfma_f32_32x32x16_bf16(a, b, c, 0, 0, 0);
}

// v_permlane32_swap_b32: a[l>=32] <- old b[l-32]; b[l<32] <- old a[l+32].
static __device__ __forceinline__ void pl32swap(unsigned& a, unsigned& b) {
  asm("v_permlane32_swap_b32 %0, %1" : "+v"(a), "+v"(b));
}

// async global->LDS DMA, 16B per lane. LDS dest = uniform base + lane*16.
static __device__ __forceinline__ void gll16(const __bf16* g, __bf16* l) {
  __builtin_amdgcn_global_load_lds(
      (const __attribute__((address_space(1))) void*)g,
      (__attribute__((address_space(3))) void*)l, 16, 0, 0);
}

static __device__ __forceinline__ void lds_barrier() {
  __asm__ volatile("s_waitcnt lgkmcnt(0)\n\ts_barrier" ::: "memory");
}
static __device__ __forceinline__ void lds_flush() {
  __asm__ volatile("s_waitcnt lgkmcnt(0)" ::: "memory");
}

static __device__ __forceinline__ float fast_exp2(float x) {
#if __has_builtin(__builtin_amdgcn_exp2f)
  return __builtin_amdgcn_exp2f(x);
#else
  return __expf(x * 0.69314718f);
#endif
}

// pack two f32 -> one dword of two bf16 (lo = a, hi = b)
static __device__ __forceinline__ unsigned pkbf(float a, float b) {
  unsigned lo = (unsigned)__builtin_bit_cast(unsigned short, (__bf16)a);
  unsigned hi = (unsigned)__builtin_bit_cast(unsigned short, (__bf16)b);
  return lo | (hi << 16);
}

// two b64 LDS reads -> one bf16_8 fragment (8B-aligned rows)
static __device__ __forceinline__ bf16_8 cat2(const __bf16* p) {
  s16x4 lo = *(const s16x4*)p;
  s16x4 hi = *(const s16x4*)(p + 4);
  s16x8 v = __builtin_shufflevector(lo, hi, 0, 1, 2, 3, 4, 5, 6, 7);
  return __builtin_bit_cast(bf16_8, v);
}

static __device__ __forceinline__ bf16_8 cvt_a_frag(const float* p) {
  f32x4 af0 = *(const f32x4*)p;
  f32x4 af1 = *(const f32x4*)(p + 4);
  bf16_8 a;
  a[0] = (__bf16)af0[0]; a[1] = (__bf16)af0[1];
  a[2] = (__bf16)af0[2]; a[3] = (__bf16)af0[3];
  a[4] = (__bf16)af1[0]; a[5] = (__bf16)af1[1];
  a[6] = (__bf16)af1[2]; a[7] = (__bf16)af1[3];
  return a;
}

// ---------- 3x 768x768 transpose + fp32->bf16 + mask bitpack, one launch ----------
// z<3: transpose W{q,k,v}. z==3, block fid==0: pack masks into bit-words:
// mbits[w] bit j = (masks[w*32 + j] != 0), w = 0..255 (B*S/32).
__global__ __launch_bounds__(256) void transpose768x3(const float* __restrict__ Wq,
                                                      const float* __restrict__ Wk,
                                                      const float* __restrict__ Wv,
                                                      __bf16* __restrict__ WtBase,
                                                      const int* __restrict__ masks,
                                                      unsigned* __restrict__ mbits) {
  int tx = threadIdx.x, ty = threadIdx.y;  // block (32,8)
  if (blockIdx.z == 3) {
    int fid = blockIdx.y * gridDim.x + blockIdx.x;
    if (fid == 0) {
      int w = ty * 32 + tx;  // 0..255
      const int* mp = masks + w * 32;
      unsigned v = 0;
#pragma unroll
      for (int j = 0; j < 32; ++j) v |= (mp[j] ? 1u : 0u) << j;
      mbits[w] = v;
    }
    return;
  }
  const float* in = blockIdx.z == 0 ? Wq : (blockIdx.z == 1 ? Wk : Wv);
  __bf16* out = WtBase + (size_t)blockIdx.z * HID * HID;
  __shared__ __bf16 tile[32][33];
  int bx = blockIdx.x * 32, by = blockIdx.y * 32;
#pragma unroll
  for (int r = 0; r < 32; r += 8)
    tile[ty + r][tx] = (__bf16)in[(size_t)(by + ty + r) * HID + bx + tx];
  __syncthreads();
#pragma unroll
  for (int r = 0; r < 32; r += 8)
    out[(size_t)(bx + ty + r) * HID + by + tx] = tile[tx][ty + r];
}

// ---------- K+V projection (R19 form, passed; aux proven insensitive) ----------
__global__ __launch_bounds__(256, 5) void proj_kv(const float* __restrict__ toks,
                                                  const __bf16* __restrict__ WtK,
                                                  const float* __restrict__ bk,
                                                  const __bf16* __restrict__ WtV,
                                                  const float* __restrict__ bv,
                                                  __bf16* __restrict__ Kout,
                                                  __bf16* __restrict__ Vtout,
                                                  int head0, int hm) {
  __shared__ __align__(16) __bf16 ldsA[2][64 * ASTR];  // 2 x 9216 B
  int tid = threadIdx.x;
  int w = tid >> 6, lane = tid & 63, l16 = lane & 15, quad = lane >> 4;
  int m0 = blockIdx.x * 64;
  int hl = blockIdx.y, h = head0 + hl;
  int srow = tid >> 2, scg = tid & 3;
  const float* asrc = toks + (size_t)(m0 + srow) * HID + scg * 8;
  const __bf16* bKrow = WtK + (size_t)(h * 64 + w * 16 + l16) * HID + quad * 8;
  const __bf16* bVrow = WtV + (size_t)(h * 64 + w * 16 + l16) * HID + quad * 8;
  f32x4 zero = {0.f, 0.f, 0.f, 0.f};
  f32x4 aK[4], aV[4];
#pragma unroll
  for (int mt = 0; mt < 4; ++mt) { aK[mt] = zero; aV[mt] = zero; }

  *(bf16_8*)(&ldsA[0][srow * ASTR + scg * 8]) = cvt_a_frag(asrc);
  *(bf16_8*)(&ldsA[0][srow * ASTR + 32 + scg * 8]) = cvt_a_frag(asrc + 32);
  __syncthreads();

  const int NCH = HID / 64;  // 12
  for (int t = 0; t < NCH; ++t) {
    int b = t & 1;
    int kk = t * 64;
    bf16_8 areg0, areg1;
    if (t + 1 < NCH) {
      areg0 = cvt_a_frag(asrc + kk + 64);
      areg1 = cvt_a_frag(asrc + kk + 96);
    }
    bf16_8 bkf0 = *(const bf16_8*)(bKrow + kk);
    bf16_8 bkf1 = *(const bf16_8*)(bKrow + kk + 32);
    bf16_8 bvf0 = *(const bf16_8*)(bVrow + kk);
    bf16_8 bvf1 = *(const bf16_8*)(bVrow + kk + 32);
#pragma unroll
    for (int mt = 0; mt < 4; ++mt) {
      bf16_8 af0 = *(const bf16_8*)(&ldsA[b][(mt * 16 + l16) * ASTR + quad * 8]);
      bf16_8 af1 = *(const bf16_8*)(&ldsA[b][(mt * 16 + l16) * ASTR + 32 + quad * 8]);
      aK[mt] = mfma16x16x32(af0, bkf0, aK[mt]);
      aK[mt] = mfma16x16x32(af1, bkf1, aK[mt]);
      aV[mt] = mfma16x16x32(af0, bvf0, aV[mt]);
      aV[mt] = mfma16x16x32(af1, bvf1, aV[mt]);
    }
    if (t + 1 < NCH) {
      *(bf16_8*)(&ldsA[b ^ 1][srow * ASTR + scg * 8]) = areg0;
      *(bf16_8*)(&ldsA[b ^ 1][srow * ASTR + 32 + scg * 8]) = areg1;
      lds_barrier();
    }
  }

  int d = w * 16 + l16;
  float bnK = bk[h * 64 + d];
  float bnV = bv[h * 64 + d];
#pragma unroll
  for (int mt = 0; mt < 4; ++mt) {
#pragma unroll
    for (int r = 0; r < 4; ++r) {
      int m = m0 + mt * 16 + quad * 4 + r;
      int b = m >> 11;
      int s = m & (SEQ - 1);
      Kout[(((size_t)b * hm + hl) * SEQ + s) * HD + d] = (__bf16)(aK[mt][r] + bnK);
      Vtout[(((size_t)b * hm + hl) * HD + d) * SEQ + s] = (__bf16)(aV[mt][r] + bnV);
    }
  }
}

// ---------- fused Q-proj + flash attention: 1-wave blocks, barrier-free ----------
// Block = 1 wave (64 thr) per (bh, 64-q tile). 32KB LDS: K0,K1,V0,V1 [64][64]
// bf16, linear, XOR-chunk-swizzled (chunk ^= row&7) on write (pre-swizzled DMA
// source) and read. Q slab aliases K region, prologue-only. Masks live as bits
// in ONE VGPR (mask_all); per tile two uniform v_readlane extract key words.
// Per body: vmcnt(16) [leaves next-tile DMA in flight] -> QK^T 32x32 swapped
// -> softmax (bit-test mask) -> in-reg P (pkbf + permlane32_swap) -> PV ->
// lgkmcnt(0) -> issue 16 DMAs for tile t+2 into the just-consumed buffer.
// No s_barrier anywhere; only loop VMEM = the 16 DMAs (count exact).
__global__ __launch_bounds__(64) void attn_fused(const float* __restrict__ toks,
                                                 const __bf16* __restrict__ WtQ,
                                                 const float* __restrict__ bq,
                                                 const __bf16* __restrict__ Kbuf,
                                                 const __bf16* __restrict__ Vtbuf,
                                                 const unsigned* __restrict__ mbits,
                                                 float* __restrict__ out,
                                                 int head0, int hm) {
  __shared__ __align__(16) __bf16 L[16384];  // K0 K1 V0 V1, 4096 elems each
  int lane = threadIdx.x & 63;
  int l16 = lane & 15, quad = lane >> 4, l32 = lane & 31, hi = lane >> 5;

  // XCD-locality remap (T1, proven)
  int nwg = gridDim.x * gridDim.y * gridDim.z;           // 1536 (A) / 128 (B)
  int hwf = blockIdx.x + gridDim.x * (blockIdx.y + gridDim.y * blockIdx.z);
  int lg = (hwf & 7) * (nwg >> 3) + (hwf >> 3);
  int q0 = (lg & (gridDim.x - 1)) * 64;                  // gridDim.x = 32
  int grp = lg / gridDim.x;
  int hl = grp % hm, bz = grp / hm;
  int h = head0 + hl;

  f32x4 zero = {0.f, 0.f, 0.f, 0.f};
  const __bf16* Kb = Kbuf + ((size_t)bz * hm + hl) * SEQ * HD;
  const __bf16* Vb = Vtbuf + ((size_t)bz * hm + hl) * HD * SEQ;

  // --- Q projection: this wave's 64 q rows, into aliased slab (prologue only) ---
  __bf16* Qs = L;  // 64*STRQ = 4352 elems, overlaps K0/K1 start (dead before DMA)
#pragma unroll
  for (int qs = 0; qs < 4; ++qs) {
    const float* arow = toks + ((size_t)bz * SEQ + q0 + qs * 16 + l16) * HID + quad * 8;
    const __bf16* brow = WtQ + (size_t)(h * 64 + l16) * HID + quad * 8;
    f32x4 qa[4] = {zero, zero, zero, zero};
    for (int kk = 0; kk < HID; kk += 32) {
      bf16_8 a = cvt_a_frag(arow + kk);
#pragma unroll
      for (int t = 0; t < 4; ++t)
        qa[t] = mfma16x16x32(a, *(const bf16_8*)(brow + (size_t)t * 16 * HID + kk), qa[t]);
    }
#pragma unroll
    for (int t = 0; t < 4; ++t) {
      float bn = bq[h * 64 + t * 16 + l16];
#pragma unroll
      for (int r = 0; r < 4; ++r)
        Qs[(qs * 16 + quad * 4 + r) * STRQ + t * 16 + l16] = (__bf16)(qa[t][r] + bn);
    }
  }
  lds_flush();  // own-wave writes visible

  // Q B-frags: lane holds Q[q = qsub*32 + l32][d = c*16 + hi*8 + j]
  bf16_8 qf[2][4];
#pragma unroll
  for (int qsub = 0; qsub < 2; ++qsub)
#pragma unroll
    for (int c = 0; c < 4; ++c)
      qf[qsub][c] = cat2(&Qs[(qsub * 32 + l32) * STRQ + c * 16 + hi * 8]);
  lds_flush();  // Q reads retired before DMA overwrites the region

  // --- mask bits: lane l holds bits for keys [l*32, l*32+32) of batch bz ---
  unsigned mask_all = mbits[bz * 64 + lane];  // 1 VMEM, drained at first use below
  unsigned qw0 = (unsigned)__builtin_amdgcn_readlane((int)mask_all, (q0 >> 5));
  unsigned qw1 = (unsigned)__builtin_amdgcn_readlane((int)mask_all, (q0 >> 5) + 1);
  bool act0 = (qw0 >> l32) & 1u;
  bool act1 = (qw1 >> l32) & 1u;
  float sm0 = act0 ? SCALE2 : 0.0f;
  float sm1 = act1 ? SCALE2 : 0.0f;
  __asm__ volatile("" ::: "memory");  // pin mask load before the DMA stream

  // --- DMA lane constants: linear LDS dest; source chunk pre-swizzled ---
  int drow = lane >> 3, dch = lane & 7;          // DMA: row-in-group, 16B chunk
  int dswz = (dch ^ drow) * 8;                   // row&7 == drow for all groups
  const __bf16* kSrc = Kb + (size_t)drow * HD + dswz;   // + (j + i*8)*HD
  const __bf16* vSrc = Vb + (size_t)drow * SEQ + dswz;  // + i*8*SEQ + j
  // read-side swizzled chunk offsets: logical chunk = c*2 + hi (c=0..3)
  int xkh = (l32 >> 1) & 3;
  int e0 = (hi ^ (l32 & 1)) << 3;                // elems
  int o0 = ((0 ^ xkh) << 4) + e0;
  int o1 = ((1 ^ xkh) << 4) + e0;
  int o2 = ((2 ^ xkh) << 4) + e0;
  int o3 = ((3 ^ xkh) << 4) + e0;

  // --- prologue DMA: tile 0 -> buf0, tile 1 -> buf1 (32 ops in flight) ---
#pragma unroll
  for (int i = 0; i < 8; ++i) gll16(kSrc + (size_t)(i * 8) * HD, &L[0 + i * 512]);
#pragma unroll
  for (int i = 0; i < 8; ++i) gll16(vSrc + (size_t)(i * 8) * SEQ + 0, &L[8192 + i * 512]);
#pragma unroll
  for (int i = 0; i < 8; ++i) gll16(kSrc + (size_t)(KVB + i * 8) * HD, &L[4096 + i * 512]);
#pragma unroll
  for (int i = 0; i < 8; ++i) gll16(vSrc + (size_t)(i * 8) * SEQ + KVB, &L[12288 + i * 512]);

  float lsum0 = 0.f, lsum1 = 0.f;
  f32x16 acc00, acc01, acc10, acc11;  // [qsub][dhalf], named (no arrays)
#pragma unroll
  for (int i = 0; i < 16; ++i) { acc00[i] = 0.f; acc01[i] = 0.f; acc10[i] = 0.f; acc11[i] = 0.f; }

  for (int t = 0; t < NKT; ++t) {
    int bufB = (t & 1) << 12;  // 4096 elems
    // current tile's 16 DMAs complete; next tile's 16 stay in flight
    __asm__ volatile("s_waitcnt vmcnt(16)" ::: "memory");
    const __bf16* LK = L + bufB;
    const __bf16* LV = L + 8192 + bufB;
    unsigned m0w = (unsigned)__builtin_amdgcn_readlane((int)mask_all, 2 * t);
    unsigned m1w = (unsigned)__builtin_amdgcn_readlane((int)mask_all, 2 * t + 1);
    unsigned mh0 = m0w >> (hi * 4);  // bit (8g+r) = key t*64 + 8g + 4hi + r
    unsigned mh1 = m1w >> (hi * 4);  // bit (8g+r) = key t*64 + 32 + 8g + 4hi + r
#pragma unroll
    for (int s = 0; s < 2; ++s) {
      unsigned mhs = s ? mh1 : mh0;
      int krow = (s * 32 + l32) * 64;
      bf16_8 kf0 = *(const bf16_8*)(LK + krow + o0);
      bf16_8 kf1 = *(const bf16_8*)(LK + krow + o1);
      bf16_8 kf2 = *(const bf16_8*)(LK + krow + o2);
      bf16_8 kf3 = *(const bf16_8*)(LK + krow + o3);
      // V B-frags: row = dhalf*32+l32; logical key-chunks s*4+hi, s*4+2+hi
      bf16_8 vf00 = *(const bf16_8*)(LV + (l32)*64 + (s ? o2 : o0));
      bf16_8 vf01 = *(const bf16_8*)(LV + (l32)*64 + (s ? o3 : o1));
      bf16_8 vf10 = *(const bf16_8*)(LV + (32 + l32) * 64 + (s ? o2 : o0));
      bf16_8 vf11 = *(const bf16_8*)(LV + (32 + l32) * 64 + (s ? o3 : o1));
#pragma unroll
      for (int qsub = 0; qsub < 2; ++qsub) {
        f32x16 st;
#pragma unroll
        for (int i = 0; i < 16; ++i) st[i] = 0.f;
        st = mfma32x32x16(kf0, qf[qsub][0], st);
        st = mfma32x32x16(kf1, qf[qsub][1], st);
        st = mfma32x32x16(kf2, qf[qsub][2], st);
        st = mfma32x32x16(kf3, qf[qsub][3], st);
        bool aq = qsub ? act1 : act0;
        float smq = qsub ? sm1 : sm0;
        // gate bit set => masked key AND active q => logit -> -1.44e31
        unsigned gate = aq ? ~mhs : 0u;
        unsigned wds[8];
        float ls = 0.f;
#pragma unroll
        for (int g = 0; g < 4; ++g) {
          float ck0 = (gate & (1u << (8 * g + 0))) ? NEGBIG2 : 0.0f;
          float ck1 = (gate & (1u << (8 * g + 1))) ? NEGBIG2 : 0.0f;
          float ck2 = (gate & (1u << (8 * g + 2))) ? NEGBIG2 : 0.0f;
          float ck3 = (gate & (1u << (8 * g + 3))) ? NEGBIG2 : 0.0f;
          float p0 = fast_exp2(fmaf(st[g * 4 + 0], smq, ck0));
          float p1 = fast_exp2(fmaf(st[g * 4 + 1], smq, ck1));
          float p2 = fast_exp2(fmaf(st[g * 4 + 2], smq, ck2));
          float p3 = fast_exp2(fmaf(st[g * 4 + 3], smq, ck3));
          ls += (p0 + p1) + (p2 + p3);
          wds[g * 2] = pkbf(p0, p1);
          wds[g * 2 + 1] = pkbf(p2, p3);
        }
        if (qsub) lsum1 += ls; else lsum0 += ls;
        pl32swap(wds[0], wds[2]);
        pl32swap(wds[1], wds[3]);
        pl32swap(wds[4], wds[6]);
        pl32swap(wds[5], wds[7]);
        u32x4 pd0 = {wds[0], wds[1], wds[2], wds[3]};
        u32x4 pd1 = {wds[4], wds[5], wds[6], wds[7]};
        bf16_8 pa0 = __builtin_bit_cast(bf16_8, pd0);  // P[q][keys s*32+0..15]
        bf16_8 pa1 = __builtin_bit_cast(bf16_8, pd1);  // P[q][keys s*32+16..31]
        if (qsub == 0) {
          acc00 = mfma32x32x16(pa1, vf01, mfma32x32x16(pa0, vf00, acc00));
          acc01 = mfma32x32x16(pa1, vf11, mfma32x32x16(pa0, vf10, acc01));
        } else {
          acc10 = mfma32x32x16(pa1, vf01, mfma32x32x16(pa0, vf00, acc10));
          acc11 = mfma32x32x16(pa1, vf11, mfma32x32x16(pa0, vf10, acc11));
        }
      }
    }
    // own LDS reads retired; then refill THIS buffer with tile t+2
    __asm__ volatile("s_waitcnt lgkmcnt(0)" ::: "memory");
    int jd = ((t + 2) & (NKT - 1)) * KVB;  // wrap: garbage reload, unused
#pragma unroll
    for (int i = 0; i < 8; ++i)
      gll16(kSrc + (size_t)(jd + i * 8) * HD, &L[bufB + i * 512]);
#pragma unroll
    for (int i = 0; i < 8; ++i)
      gll16(vSrc + (size_t)(i * 8) * SEQ + jd, &L[8192 + bufB + i * 512]);
  }
  __asm__ volatile("s_waitcnt vmcnt(0)" ::: "memory");  // drain tail DMAs

  // --- normalize + store (epilogue-only cross-lane) ---
#pragma unroll
  for (int qsub = 0; qsub < 2; ++qsub) {
    float v = qsub ? lsum1 : lsum0;
    v += __shfl_xor(v, 32);
    float linv = 1.0f / v;  // valid for q = q0 + qsub*32 + l32
#pragma unroll
    for (int r = 0; r < 16; ++r) {
      int row = (r & 3) + 8 * (r >> 2) + 4 * hi;
      float sc = __shfl(linv, row);
      size_t orow = (size_t)bz * SEQ + q0 + qsub * 32 + row;
      out[orow * HID + h * HD + l32] = (qsub ? acc10[r] : acc00[r]) * sc;
      out[orow * HID + h * HD + 32 + l32] = (qsub ? acc11[r] : acc01[r]) * sc;
    }
  }
}

extern "C" void kernel_launch(void* const* d_in, const int* in_sizes, int n_in,
                              void* d_out, int out_size, void* d_ws, size_t ws_size,
                              hipStream_t stream) {
  (void)in_sizes; (void)n_in; (void)out_size;
  const float* toks = (const float*)d_in[0];
  const int* masks = (const int*)d_in[1];
  const float* Wq = (const float*)d_in[2];
  const float* bq = (const float*)d_in[3];
  const float* Wk = (const float*)d_in[4];
  const float* bk = (const float*)d_in[5];
  const float* Wv = (const float*)d_in[6];
  const float* bv = (const float*)d_in[7];
  char* ws = (char*)d_ws;
  const size_t MB_B = 1024;  // unsigned[256] mask bit-words
  const size_t WT_B = (size_t)HID * HID * 2;
  const size_t KV_FULL_B = (size_t)BATCH * NHEADS * SEQ * HD * 2;
  const size_t KV_HEAD_B = (size_t)BATCH * SEQ * HD * 2;
  const size_t TIER_A_NEED = MB_B + 3 * WT_B + 2 * KV_FULL_B;  // ~28.7 MB
  unsigned* mbits = (unsigned*)(ws);
  __bf16* WtQ = (__bf16*)(ws + MB_B + 0 * WT_B);
  __bf16* WtK = (__bf16*)(ws + MB_B + 1 * WT_B);
  __bf16* WtV = (__bf16*)(ws + MB_B + 2 * WT_B);
  float* outp = (float*)d_out;

  dim3 tgrid(HID / 32, HID / 32, 4), tblk(32, 8);
  transpose768x3<<<tgrid, tblk, 0, stream>>>(Wq, Wk, Wv, WtQ, masks, mbits);

  if (ws_size >= TIER_A_NEED) {
    __bf16* Kf = (__bf16*)(ws + MB_B + 3 * WT_B);
    __bf16* Vtf = (__bf16*)(ws + MB_B + 3 * WT_B + KV_FULL_B);
    dim3 pgrid(BATCH * SEQ / 64, NHEADS);
    proj_kv<<<pgrid, 256, 0, stream>>>(toks, WtK, bk, WtV, bv, Kf, Vtf, 0, NHEADS);
    dim3 agrid(SEQ / 64, NHEADS, BATCH);
    attn_fused<<<agrid, 64, 0, stream>>>(toks, WtQ, bq, Kf, Vtf, mbits, outp, 0, NHEADS);
  } else {
    __bf16* Kh = (__bf16*)(ws + MB_B + 3 * WT_B);
    __bf16* Vth = (__bf16*)(ws + MB_B + 3 * WT_B + KV_HEAD_B);
    dim3 pgrid(BATCH * SEQ / 64, 1);
    dim3 agrid(SEQ / 64, 1, BATCH);
    for (int h = 0; h < NHEADS; ++h) {
      proj_kv<<<pgrid, 256, 0, stream>>>(toks, WtK, bk, WtV, bv, Kh, Vth, h, 1);
      attn_fused<<<agrid, 64, 0, stream>>>(toks, WtQ, bq, Kh, Vth, mbits, outp, h, 1);
    }
  }
}

// Round 10
// 302.234 us; speedup vs baseline: 1.4342x; 1.4342x over previous
//
#include <hip/hip_runtime.h>
#include <hip/hip_bf16.h>
#include <cstddef>

// MHAttention forward, MI355X/gfx950.
// Dtype contract (R0-R3): inputs fp32 (toks, W*, b*; masks int32), OUTPUT fp32.
// Internals: bf16 MFMA fragments, fp32 accumulation.
// R21 -> R22 post-mortem: R21 (1-wave blocks, DMA, in-reg P) PASSED and its
// per-wave efficiency was 3x R12 (0.44 vs 0.15 pairs/cy/wave) -- but occupancy
// collapsed to 2.4 waves/CU (7.4%), exposing the per-tile DMA wait. The math/
// addressing (swizzled global_load_lds, in-reg P via pkbf+permlane32_swap,
// bitmask softmax) are all HW-verified. R22 = same verified machinery at real
// residency: 256-thread blocks of 4 INDEPENDENT waves (each owns 32 q) sharing
// one DMA-staged K/V double buffer. Per tile: vmcnt(4) (own share; next tile's
// 4 stay in flight, T4) + barrier -> ds_reads + MFMA + in-reg softmax/P ->
// lgkmcnt(0) + barrier -> issue own 4 DMAs for t+2. Loop VMEM = exactly 4
// DMAs/wave (provably clean count, R20 lesson); ZERO LDS writes in loop; P
// never touches memory. Grid 768 = 3 blocks/CU exact -> 12 waves/CU.
// LDS: K0,K1,V0,V1 @0..16383 + Q slab @16384 (128 x 68) = 50176 B.

typedef __bf16 bf16_8 __attribute__((ext_vector_type(8)));
typedef float f32x4 __attribute__((ext_vector_type(4)));
typedef float f32x16 __attribute__((ext_vector_type(16)));
typedef short s16x4 __attribute__((ext_vector_type(4)));
typedef short s16x8 __attribute__((ext_vector_type(8)));
typedef unsigned int u32x4 __attribute__((ext_vector_type(4)));

#define HID 768
#define NHEADS 12
#define HD 64
#define BATCH 4
#define SEQ 2048
#define NEGBIG2 (-1.44269504e31f)  // -1e31 * log2e, exp2 -> 0
#define SCALE2 0.18033688f         // 0.125 * log2e

#define KVB 64           // keys per tile
#define NKT (SEQ / KVB)  // 32
#define STRQ 68          // Q slab row stride (padded, prologue only)
#define ASTR 72          // proj LDS row stride (elems)

static __device__ __forceinline__ f32x4 mfma16x16x32(bf16_8 a, bf16_8 b, f32x4 c) {
  return __builtin_amdgcn_mfma_f32_16x16x32_bf16(a, b, c, 0, 0, 0);
}
static __device__ __forceinline__ f32x16 mfma32x32x16(bf16_8 a, bf16_8 b, f32x16 c) {
  return __builtin_amdgcn_mfma_f32_32x32x16_bf16(a, b, c, 0, 0, 0);
}

// v_permlane32_swap_b32: a[l>=32] <- old b[l-32]; b[l<32] <- old a[l+32].
static __device__ __forceinline__ void pl32swap(unsigned& a, unsigned& b) {
  asm("v_permlane32_swap_b32 %0, %1" : "+v"(a), "+v"(b));
}

// async global->LDS DMA, 16B per lane. LDS dest = uniform base + lane*16.
static __device__ __forceinline__ void gll16(const __bf16* g, __bf16* l) {
  __builtin_amdgcn_global_load_lds(
      (const __attribute__((address_space(1))) void*)g,
      (__attribute__((address_space(3))) void*)l, 16, 0, 0);
}

static __device__ __forceinline__ void lds_barrier() {
  __asm__ volatile("s_waitcnt lgkmcnt(0)\n\ts_barrier" ::: "memory");
}
static __device__ __forceinline__ void lds_flush() {
  __asm__ volatile("s_waitcnt lgkmcnt(0)" ::: "memory");
}

static __device__ __forceinline__ float fast_exp2(float x) {
#if __has_builtin(__builtin_amdgcn_exp2f)
  return __builtin_amdgcn_exp2f(x);
#else
  return __expf(x * 0.69314718f);
#endif
}

// pack two f32 -> one dword of two bf16 (lo = a, hi = b)
static __device__ __forceinline__ unsigned pkbf(float a, float b) {
  unsigned lo = (unsigned)__builtin_bit_cast(unsigned short, (__bf16)a);
  unsigned hi = (unsigned)__builtin_bit_cast(unsigned short, (__bf16)b);
  return lo | (hi << 16);
}

// two b64 LDS reads -> one bf16_8 fragment (8B-aligned rows)
static __device__ __forceinline__ bf16_8 cat2(const __bf16* p) {
  s16x4 lo = *(const s16x4*)p;
  s16x4 hi = *(const s16x4*)(p + 4);
  s16x8 v = __builtin_shufflevector(lo, hi, 0, 1, 2, 3, 4, 5, 6, 7);
  return __builtin_bit_cast(bf16_8, v);
}

static __device__ __forceinline__ bf16_8 cvt_a_frag(const float* p) {
  f32x4 af0 = *(const f32x4*)p;
  f32x4 af1 = *(const f32x4*)(p + 4);
  bf16_8 a;
  a[0] = (__bf16)af0[0]; a[1] = (__bf16)af0[1];
  a[2] = (__bf16)af0[2]; a[3] = (__bf16)af0[3];
  a[4] = (__bf16)af1[0]; a[5] = (__bf16)af1[1];
  a[6] = (__bf16)af1[2]; a[7] = (__bf16)af1[3];
  return a;
}

// ---------- 3x 768x768 transpose + fp32->bf16 + mask bitpack, one launch ----------
__global__ __launch_bounds__(256) void transpose768x3(const float* __restrict__ Wq,
                                                      const float* __restrict__ Wk,
                                                      const float* __restrict__ Wv,
                                                      __bf16* __restrict__ WtBase,
                                                      const int* __restrict__ masks,
                                                      unsigned* __restrict__ mbits) {
  int tx = threadIdx.x, ty = threadIdx.y;  // block (32,8)
  if (blockIdx.z == 3) {
    int fid = blockIdx.y * gridDim.x + blockIdx.x;
    if (fid == 0) {
      int w = ty * 32 + tx;  // 0..255
      const int* mp = masks + w * 32;
      unsigned v = 0;
#pragma unroll
      for (int j = 0; j < 32; ++j) v |= (mp[j] ? 1u : 0u) << j;
      mbits[w] = v;
    }
    return;
  }
  const float* in = blockIdx.z == 0 ? Wq : (blockIdx.z == 1 ? Wk : Wv);
  __bf16* out = WtBase + (size_t)blockIdx.z * HID * HID;
  __shared__ __bf16 tile[32][33];
  int bx = blockIdx.x * 32, by = blockIdx.y * 32;
#pragma unroll
  for (int r = 0; r < 32; r += 8)
    tile[ty + r][tx] = (__bf16)in[(size_t)(by + ty + r) * HID + bx + tx];
  __syncthreads();
#pragma unroll
  for (int r = 0; r < 32; r += 8)
    out[(size_t)(bx + ty + r) * HID + by + tx] = tile[tx][ty + r];
}

// ---------- K+V projection (R21 form, passed; aux proven insensitive) ----------
__global__ __launch_bounds__(256, 5) void proj_kv(const float* __restrict__ toks,
                                                  const __bf16* __restrict__ WtK,
                                                  const float* __restrict__ bk,
                                                  const __bf16* __restrict__ WtV,
                                                  const float* __restrict__ bv,
                                                  __bf16* __restrict__ Kout,
                                                  __bf16* __restrict__ Vtout,
                                                  int head0, int hm) {
  __shared__ __align__(16) __bf16 ldsA[2][64 * ASTR];  // 2 x 9216 B
  int tid = threadIdx.x;
  int w = tid >> 6, lane = tid & 63, l16 = lane & 15, quad = lane >> 4;
  int m0 = blockIdx.x * 64;
  int hl = blockIdx.y, h = head0 + hl;
  int srow = tid >> 2, scg = tid & 3;
  const float* asrc = toks + (size_t)(m0 + srow) * HID + scg * 8;
  const __bf16* bKrow = WtK + (size_t)(h * 64 + w * 16 + l16) * HID + quad * 8;
  const __bf16* bVrow = WtV + (size_t)(h * 64 + w * 16 + l16) * HID + quad * 8;
  f32x4 zero = {0.f, 0.f, 0.f, 0.f};
  f32x4 aK[4], aV[4];
#pragma unroll
  for (int mt = 0; mt < 4; ++mt) { aK[mt] = zero; aV[mt] = zero; }

  *(bf16_8*)(&ldsA[0][srow * ASTR + scg * 8]) = cvt_a_frag(asrc);
  *(bf16_8*)(&ldsA[0][srow * ASTR + 32 + scg * 8]) = cvt_a_frag(asrc + 32);
  __syncthreads();

  const int NCH = HID / 64;  // 12
  for (int t = 0; t < NCH; ++t) {
    int b = t & 1;
    int kk = t * 64;
    bf16_8 areg0, areg1;
    if (t + 1 < NCH) {
      areg0 = cvt_a_frag(asrc + kk + 64);
      areg1 = cvt_a_frag(asrc + kk + 96);
    }
    bf16_8 bkf0 = *(const bf16_8*)(bKrow + kk);
    bf16_8 bkf1 = *(const bf16_8*)(bKrow + kk + 32);
    bf16_8 bvf0 = *(const bf16_8*)(bVrow + kk);
    bf16_8 bvf1 = *(const bf16_8*)(bVrow + kk + 32);
#pragma unroll
    for (int mt = 0; mt < 4; ++mt) {
      bf16_8 af0 = *(const bf16_8*)(&ldsA[b][(mt * 16 + l16) * ASTR + quad * 8]);
      bf16_8 af1 = *(const bf16_8*)(&ldsA[b][(mt * 16 + l16) * ASTR + 32 + quad * 8]);
      aK[mt] = mfma16x16x32(af0, bkf0, aK[mt]);
      aK[mt] = mfma16x16x32(af1, bkf1, aK[mt]);
      aV[mt] = mfma16x16x32(af0, bvf0, aV[mt]);
      aV[mt] = mfma16x16x32(af1, bvf1, aV[mt]);
    }
    if (t + 1 < NCH) {
      *(bf16_8*)(&ldsA[b ^ 1][srow * ASTR + scg * 8]) = areg0;
      *(bf16_8*)(&ldsA[b ^ 1][srow * ASTR + 32 + scg * 8]) = areg1;
      lds_barrier();
    }
  }

  int d = w * 16 + l16;
  float bnK = bk[h * 64 + d];
  float bnV = bv[h * 64 + d];
#pragma unroll
  for (int mt = 0; mt < 4; ++mt) {
#pragma unroll
    for (int r = 0; r < 4; ++r) {
      int m = m0 + mt * 16 + quad * 4 + r;
      int b = m >> 11;
      int s = m & (SEQ - 1);
      Kout[(((size_t)b * hm + hl) * SEQ + s) * HD + d] = (__bf16)(aK[mt][r] + bnK);
      Vtout[(((size_t)b * hm + hl) * HD + d) * SEQ + s] = (__bf16)(aV[mt][r] + bnV);
    }
  }
}

// ---------- fused Q-proj + flash attention: 4 indep waves, shared DMA K/V ----------
// Block 256 thr = 4 waves, each owning 32 q (q = q0b + w*32 + l32) of one
// (b,h). Shared K/V double buffer (R21-verified swizzled DMA layout); per tile
// each wave issues 4 of the 16 DMAs. Sync = vmcnt(4)+barrier (tile ready) and
// lgkmcnt(0)+barrier (reads done) -- counted vmcnt never drains the prefetch.
// In-register P (R21-verified pkbf+permlane32_swap); bitmask softmax via
// readlane from one pre-loaded VGPR. Loop has ZERO LDS writes, ZERO loop VMEM
// except the 4 DMAs.
__global__ __launch_bounds__(256, 3) void attn_fused(const float* __restrict__ toks,
                                                     const __bf16* __restrict__ WtQ,
                                                     const float* __restrict__ bq,
                                                     const __bf16* __restrict__ Kbuf,
                                                     const __bf16* __restrict__ Vtbuf,
                                                     const unsigned* __restrict__ mbits,
                                                     float* __restrict__ out,
                                                     int head0, int hm) {
  __shared__ __align__(16) __bf16 L[25088];  // K0@0 K1@4096 V0@8192 V1@12288 Q@16384
  int tid = threadIdx.x;
  int w = tid >> 6, lane = tid & 63;
  int l16 = lane & 15, quad = lane >> 4, l32 = lane & 31, hi = lane >> 5;

  // XCD-locality remap (T1, proven)
  int nwg = gridDim.x * gridDim.y * gridDim.z;           // 768 (A) / 64 (B)
  int hwf = blockIdx.x + gridDim.x * (blockIdx.y + gridDim.y * blockIdx.z);
  int lg = (hwf & 7) * (nwg >> 3) + (hwf >> 3);
  int q0b = (lg & (gridDim.x - 1)) * 128;                // gridDim.x = 16
  int grp = lg / gridDim.x;
  int hl = grp % hm, bz = grp / hm;
  int h = head0 + hl;

  f32x4 zero = {0.f, 0.f, 0.f, 0.f};
  const __bf16* Kb = Kbuf + ((size_t)bz * hm + hl) * SEQ * HD;
  const __bf16* Vb = Vtbuf + ((size_t)bz * hm + hl) * HD * SEQ;

  // --- mask bits FIRST (oldest VMEM; retires before DMAs by in-order rule) ---
  unsigned mask_all = mbits[bz * 64 + lane];

  // --- DMA lane constants (R21-verified): linear dest, pre-swizzled source ---
  int drow = lane >> 3, dch = lane & 7;
  int dswz = (dch ^ drow) * 8;  // row&7 == drow for every 8-row DMA group
  const __bf16* kSrc = Kb + (size_t)drow * HD + dswz;
  const __bf16* vSrc = Vb + (size_t)drow * SEQ + dswz;
  int gk0 = 2 * w, gk1 = 2 * w + 1;  // this wave's K/V DMA groups

  // --- issue prologue DMAs (tiles 0,1) BEFORE Q-proj: latency hides under it.
  // In-order vmcnt retirement makes Q-proj's compiler waits absorb the drain.
  gll16(kSrc + (size_t)(gk0 * 8) * HD, &L[0 + gk0 * 512]);
  gll16(kSrc + (size_t)(gk1 * 8) * HD, &L[0 + gk1 * 512]);
  gll16(vSrc + (size_t)(gk0 * 8) * SEQ + 0, &L[8192 + gk0 * 512]);
  gll16(vSrc + (size_t)(gk1 * 8) * SEQ + 0, &L[8192 + gk1 * 512]);
  gll16(kSrc + (size_t)(KVB + gk0 * 8) * HD, &L[4096 + gk0 * 512]);
  gll16(kSrc + (size_t)(KVB + gk1 * 8) * HD, &L[4096 + gk1 * 512]);
  gll16(vSrc + (size_t)(gk0 * 8) * SEQ + KVB, &L[12288 + gk0 * 512]);
  gll16(vSrc + (size_t)(gk1 * 8) * SEQ + KVB, &L[12288 + gk1 * 512]);

  // --- Q projection: wave w -> rows q0b + w*32 .. +32 into private Q slab ---
  __bf16* Qs = &L[16384 + (w * 32) * STRQ];
#pragma unroll
  for (int qs = 0; qs < 2; ++qs) {
    const float* arow =
        toks + ((size_t)bz * SEQ + q0b + w * 32 + qs * 16 + l16) * HID + quad * 8;
    const __bf16* brow = WtQ + (size_t)(h * 64 + l16) * HID + quad * 8;
    f32x4 qa[4] = {zero, zero, zero, zero};
    for (int kk = 0; kk < HID; kk += 32) {
      bf16_8 a = cvt_a_frag(arow + kk);
#pragma unroll
      for (int t = 0; t < 4; ++t)
        qa[t] = mfma16x16x32(a, *(const bf16_8*)(brow + (size_t)t * 16 * HID + kk), qa[t]);
    }
#pragma unroll
    for (int t = 0; t < 4; ++t) {
      float bn = bq[h * 64 + t * 16 + l16];
#pragma unroll
      for (int r = 0; r < 4; ++r)
        Qs[(qs * 16 + quad * 4 + r) * STRQ + t * 16 + l16] = (__bf16)(qa[t][r] + bn);
    }
  }
  lds_flush();  // own-wave Q writes visible (slab is wave-private)

  // Q B-frags: lane holds Q[q = w*32 + l32][d = c*16 + hi*8 + j]  (R18-verified)
  bf16_8 qf0 = cat2(&Qs[l32 * STRQ + 0 * 16 + hi * 8]);
  bf16_8 qf1 = cat2(&Qs[l32 * STRQ + 1 * 16 + hi * 8]);
  bf16_8 qf2 = cat2(&Qs[l32 * STRQ + 2 * 16 + hi * 8]);
  bf16_8 qf3 = cat2(&Qs[l32 * STRQ + 3 * 16 + hi * 8]);
  unsigned qw = (unsigned)__builtin_amdgcn_readlane((int)mask_all, (q0b >> 5) + w);
  bool act = (qw >> l32) & 1u;
  float smq = act ? SCALE2 : 0.0f;

  // read-side swizzled chunk offsets (R21-verified)
  int xkh = (l32 >> 1) & 3;
  int e0 = (hi ^ (l32 & 1)) << 3;
  int o0 = ((0 ^ xkh) << 4) + e0;
  int o1 = ((1 ^ xkh) << 4) + e0;
  int o2 = ((2 ^ xkh) << 4) + e0;
  int o3 = ((3 ^ xkh) << 4) + e0;

  float lsum = 0.f;
  f32x16 acc0, acc1;  // [dhalf], named
#pragma unroll
  for (int i = 0; i < 16; ++i) { acc0[i] = 0.f; acc1[i] = 0.f; }

  for (int t = 0; t < NKT; ++t) {
    int bufB = (t & 1) << 12;  // 4096 elems
    // own share of tile t landed (t+1's 4 stay in flight); then all waves'
    __asm__ volatile("s_waitcnt vmcnt(4)\n\ts_barrier" ::: "memory");
    const __bf16* LK = L + bufB;
    const __bf16* LV = L + 8192 + bufB;
    unsigned m0w = (unsigned)__builtin_amdgcn_readlane((int)mask_all, 2 * t);
    unsigned m1w = (unsigned)__builtin_amdgcn_readlane((int)mask_all, 2 * t + 1);
    unsigned mh0 = m0w >> (hi * 4);
    unsigned mh1 = m1w >> (hi * 4);
#pragma unroll
    for (int s = 0; s < 2; ++s) {
      unsigned mhs = s ? mh1 : mh0;
      int krow = (s * 32 + l32) * 64;
      bf16_8 kf0 = *(const bf16_8*)(LK + krow + o0);
      bf16_8 kf1 = *(const bf16_8*)(LK + krow + o1);
      bf16_8 kf2 = *(const bf16_8*)(LK + krow + o2);
      bf16_8 kf3 = *(const bf16_8*)(LK + krow + o3);
      bf16_8 vf00 = *(const bf16_8*)(LV + (l32)*64 + (s ? o2 : o0));
      bf16_8 vf01 = *(const bf16_8*)(LV + (l32)*64 + (s ? o3 : o1));
      bf16_8 vf10 = *(const bf16_8*)(LV + (32 + l32) * 64 + (s ? o2 : o0));
      bf16_8 vf11 = *(const bf16_8*)(LV + (32 + l32) * 64 + (s ? o3 : o1));
      // --- QK^T: S^T[key = s*32 + (r&3)+8*(r>>2)+4*hi][q = w*32 + l32] ---
      f32x16 st;
#pragma unroll
      for (int i = 0; i < 16; ++i) st[i] = 0.f;
      st = mfma32x32x16(kf0, qf0, st);
      st = mfma32x32x16(kf1, qf1, st);
      st = mfma32x32x16(kf2, qf2, st);
      st = mfma32x32x16(kf3, qf3, st);
      // --- softmax numerators via bitmask (R21-verified) ---
      unsigned gate = act ? ~mhs : 0u;
      unsigned wds[8];
      float ls = 0.f;
#pragma unroll
      for (int g = 0; g < 4; ++g) {
        float ck0 = (gate & (1u << (8 * g + 0))) ? NEGBIG2 : 0.0f;
        float ck1 = (gate & (1u << (8 * g + 1))) ? NEGBIG2 : 0.0f;
        float ck2 = (gate & (1u << (8 * g + 2))) ? NEGBIG2 : 0.0f;
        float ck3 = (gate & (1u << (8 * g + 3))) ? NEGBIG2 : 0.0f;
        float p0 = fast_exp2(fmaf(st[g * 4 + 0], smq, ck0));
        float p1 = fast_exp2(fmaf(st[g * 4 + 1], smq, ck1));
        float p2 = fast_exp2(fmaf(st[g * 4 + 2], smq, ck2));
        float p3 = fast_exp2(fmaf(st[g * 4 + 3], smq, ck3));
        ls += (p0 + p1) + (p2 + p3);
        wds[g * 2] = pkbf(p0, p1);
        wds[g * 2 + 1] = pkbf(p2, p3);
      }
      lsum += ls;
      // --- in-register P -> PV A-frags (R21-verified) ---
      pl32swap(wds[0], wds[2]);
      pl32swap(wds[1], wds[3]);
      pl32swap(wds[4], wds[6]);
      pl32swap(wds[5], wds[7]);
      u32x4 pd0 = {wds[0], wds[1], wds[2], wds[3]};
      u32x4 pd1 = {wds[4], wds[5], wds[6], wds[7]};
      bf16_8 pa0 = __builtin_bit_cast(bf16_8, pd0);  // P[q][keys s*32+0..15]
      bf16_8 pa1 = __builtin_bit_cast(bf16_8, pd1);  // P[q][keys s*32+16..31]
      acc0 = mfma32x32x16(pa1, vf01, mfma32x32x16(pa0, vf00, acc0));
      acc1 = mfma32x32x16(pa1, vf11, mfma32x32x16(pa0, vf10, acc1));
    }
    // all waves' reads of buf done -> safe to overwrite; then own 4 DMAs (t+2)
    __asm__ volatile("s_waitcnt lgkmcnt(0)\n\ts_barrier" ::: "memory");
    int jd = ((t + 2) & (NKT - 1)) * KVB;  // wrap: garbage reload, unused
    gll16(kSrc + (size_t)(jd + gk0 * 8) * HD, &L[bufB + gk0 * 512]);
    gll16(kSrc + (size_t)(jd + gk1 * 8) * HD, &L[bufB + gk1 * 512]);
    gll16(vSrc + (size_t)(gk0 * 8) * SEQ + jd, &L[8192 + bufB + gk0 * 512]);
    gll16(vSrc + (size_t)(gk1 * 8) * SEQ + jd, &L[8192 + bufB + gk1 * 512]);
  }
  __asm__ volatile("s_waitcnt vmcnt(0)" ::: "memory");  // drain tail DMAs

  // --- normalize + store (epilogue-only cross-lane; R21-verified map) ---
  float v = lsum;
  v += __shfl_xor(v, 32);
  float linv = 1.0f / v;  // valid for q = q0b + w*32 + l32
#pragma unroll
  for (int r = 0; r < 16; ++r) {
    int row = (r & 3) + 8 * (r >> 2) + 4 * hi;
    float sc = __shfl(linv, row);
    size_t orow = (size_t)bz * SEQ + q0b + w * 32 + row;
    out[orow * HID + h * HD + l32] = acc0[r] * sc;
    out[orow * HID + h * HD + 32 + l32] = acc1[r] * sc;
  }
}

extern "C" void kernel_launch(void* const* d_in, const int* in_sizes, int n_in,
                              void* d_out, int out_size, void* d_ws, size_t ws_size,
                              hipStream_t stream) {
  (void)in_sizes; (void)n_in; (void)out_size;
  const float* toks = (const float*)d_in[0];
  const int* masks = (const int*)d_in[1];
  const float* Wq = (const float*)d_in[2];
  const float* bq = (const float*)d_in[3];
  const float* Wk = (const float*)d_in[4];
  const float* bk = (const float*)d_in[5];
  const float* Wv = (const float*)d_in[6];
  const float* bv = (const float*)d_in[7];
  char* ws = (char*)d_ws;
  const size_t MB_B = 1024;  // unsigned[256] mask bit-words
  const size_t WT_B = (size_t)HID * HID * 2;
  const size_t KV_FULL_B = (size_t)BATCH * NHEADS * SEQ * HD * 2;
  const size_t KV_HEAD_B = (size_t)BATCH * SEQ * HD * 2;
  const size_t TIER_A_NEED = MB_B + 3 * WT_B + 2 * KV_FULL_B;  // ~28.7 MB
  unsigned* mbits = (unsigned*)(ws);
  __bf16* WtQ = (__bf16*)(ws + MB_B + 0 * WT_B);
  __bf16* WtK = (__bf16*)(ws + MB_B + 1 * WT_B);
  __bf16* WtV = (__bf16*)(ws + MB_B + 2 * WT_B);
  float* outp = (float*)d_out;

  dim3 tgrid(HID / 32, HID / 32, 4), tblk(32, 8);
  transpose768x3<<<tgrid, tblk, 0, stream>>>(Wq, Wk, Wv, WtQ, masks, mbits);

  if (ws_size >= TIER_A_NEED) {
    __bf16* Kf = (__bf16*)(ws + MB_B + 3 * WT_B);
    __bf16* Vtf = (__bf16*)(ws + MB_B + 3 * WT_B + KV_FULL_B);
    dim3 pgrid(BATCH * SEQ / 64, NHEADS);
    proj_kv<<<pgrid, 256, 0, stream>>>(toks, WtK, bk, WtV, bv, Kf, Vtf, 0, NHEADS);
    dim3 agrid(SEQ / 128, NHEADS, BATCH);
    attn_fused<<<agrid, 256, 0, stream>>>(toks, WtQ, bq, Kf, Vtf, mbits, outp, 0, NHEADS);
  } else {
    __bf16* Kh = (__bf16*)(ws + MB_B + 3 * WT_B);
    __bf16* Vth = (__bf16*)(ws + MB_B + 3 * WT_B + KV_HEAD_B);
    dim3 pgrid(BATCH * SEQ / 64, 1);
    dim3 agrid(SEQ / 128, 1, BATCH);
    for (int h = 0; h < NHEADS; ++h) {
      proj_kv<<<pgrid, 256, 0, stream>>>(toks, WtK, bk, WtV, bv, Kh, Vth, h, 1);
      attn_fused<<<agrid, 256, 0, stream>>>(toks, WtQ, bq, Kh, Vth, mbits, outp, h, 1);
    }
  }
}

// Round 11
// 297.883 us; speedup vs baseline: 1.4552x; 1.0146x over previous
//
#include <hip/hip_runtime.h>
#include <hip/hip_bf16.h>
#include <cstddef>

// MHAttention forward, MI355X/gfx950.
// Dtype contract (R0-R3): inputs fp32 (toks, W*, b*; masks int32), OUTPUT fp32.
// Internals: bf16 MFMA fragments, fp32 accumulation.
// R22 -> R23 post-mortem: R22 = best yet (178us attn, 302 total) but far from
// predicted -- the eleventh structure inside the 1.6-1.9 pairs/cy/CU band.
// Last unfalsified suspect in R22's schedule: per-tile DMA wait (tile t+1
// issued at BOTTOM of t-1, waited at top of t+1 -- one body of slack) plus two
// barriers/iter. R23: TRIPLE-buffered K/V, ONE barrier/iter, DMA issue at TOP:
// iter t = vmcnt(4) [tile t ready, t+1 in flight] -> s_barrier [all waves
// done reading buf((t+2)%3) last iter] -> issue tile t+2 into buf((t+2)%3)
// -> body. Slack = 2 full bodies; barrier count halved; loop VMEM still
// exactly 4 DMAs/wave (clean count, R20 lesson). Q slab (prologue-only,
// stride 64 = 8192 elems) ALIASES buffer 2 -- its first DMA is issued only
// after the iter-0 barrier, when all waves have extracted Q frags. LDS 49152B
// -> still 3 blocks/CU, 12 waves. All R21/R22-verified machinery unchanged
// (swizzled global_load_lds, in-reg P pkbf+permlane32_swap, bitmask softmax).

typedef __bf16 bf16_8 __attribute__((ext_vector_type(8)));
typedef float f32x4 __attribute__((ext_vector_type(4)));
typedef float f32x16 __attribute__((ext_vector_type(16)));
typedef short s16x4 __attribute__((ext_vector_type(4)));
typedef short s16x8 __attribute__((ext_vector_type(8)));
typedef unsigned int u32x4 __attribute__((ext_vector_type(4)));

#define HID 768
#define NHEADS 12
#define HD 64
#define BATCH 4
#define SEQ 2048
#define NEGBIG2 (-1.44269504e31f)  // -1e31 * log2e, exp2 -> 0
#define SCALE2 0.18033688f         // 0.125 * log2e

#define KVB 64           // keys per tile
#define NKT (SEQ / KVB)  // 32
#define STRQ 64          // Q slab row stride (aliases buffer 2; prologue only)
#define ASTR 72          // proj LDS row stride (elems)

static __device__ __forceinline__ f32x4 mfma16x16x32(bf16_8 a, bf16_8 b, f32x4 c) {
  return __builtin_amdgcn_mfma_f32_16x16x32_bf16(a, b, c, 0, 0, 0);
}
static __device__ __forceinline__ f32x16 mfma32x32x16(bf16_8 a, bf16_8 b, f32x16 c) {
  return __builtin_amdgcn_mfma_f32_32x32x16_bf16(a, b, c, 0, 0, 0);
}

// v_permlane32_swap_b32: a[l>=32] <- old b[l-32]; b[l<32] <- old a[l+32].
static __device__ __forceinline__ void pl32swap(unsigned& a, unsigned& b) {
  asm("v_permlane32_swap_b32 %0, %1" : "+v"(a), "+v"(b));
}

// async global->LDS DMA, 16B per lane. LDS dest = uniform base + lane*16.
static __device__ __forceinline__ void gll16(const __bf16* g, __bf16* l) {
  __builtin_amdgcn_global_load_lds(
      (const __attribute__((address_space(1))) void*)g,
      (__attribute__((address_space(3))) void*)l, 16, 0, 0);
}

static __device__ __forceinline__ void lds_barrier() {
  __asm__ volatile("s_waitcnt lgkmcnt(0)\n\ts_barrier" ::: "memory");
}
static __device__ __forceinline__ void lds_flush() {
  __asm__ volatile("s_waitcnt lgkmcnt(0)" ::: "memory");
}

static __device__ __forceinline__ float fast_exp2(float x) {
#if __has_builtin(__builtin_amdgcn_exp2f)
  return __builtin_amdgcn_exp2f(x);
#else
  return __expf(x * 0.69314718f);
#endif
}

// pack two f32 -> one dword of two bf16 (lo = a, hi = b)
static __device__ __forceinline__ unsigned pkbf(float a, float b) {
  unsigned lo = (unsigned)__builtin_bit_cast(unsigned short, (__bf16)a);
  unsigned hi = (unsigned)__builtin_bit_cast(unsigned short, (__bf16)b);
  return lo | (hi << 16);
}

// two b64 LDS reads -> one bf16_8 fragment (8B-aligned rows)
static __device__ __forceinline__ bf16_8 cat2(const __bf16* p) {
  s16x4 lo = *(const s16x4*)p;
  s16x4 hi = *(const s16x4*)(p + 4);
  s16x8 v = __builtin_shufflevector(lo, hi, 0, 1, 2, 3, 4, 5, 6, 7);
  return __builtin_bit_cast(bf16_8, v);
}

static __device__ __forceinline__ bf16_8 cvt_a_frag(const float* p) {
  f32x4 af0 = *(const f32x4*)p;
  f32x4 af1 = *(const f32x4*)(p + 4);
  bf16_8 a;
  a[0] = (__bf16)af0[0]; a[1] = (__bf16)af0[1];
  a[2] = (__bf16)af0[2]; a[3] = (__bf16)af0[3];
  a[4] = (__bf16)af1[0]; a[5] = (__bf16)af1[1];
  a[6] = (__bf16)af1[2]; a[7] = (__bf16)af1[3];
  return a;
}

// ---------- 3x 768x768 transpose + fp32->bf16 + mask bitpack, one launch ----------
__global__ __launch_bounds__(256) void transpose768x3(const float* __restrict__ Wq,
                                                      const float* __restrict__ Wk,
                                                      const float* __restrict__ Wv,
                                                      __bf16* __restrict__ WtBase,
                                                      const int* __restrict__ masks,
                                                      unsigned* __restrict__ mbits) {
  int tx = threadIdx.x, ty = threadIdx.y;  // block (32,8)
  if (blockIdx.z == 3) {
    int fid = blockIdx.y * gridDim.x + blockIdx.x;
    if (fid == 0) {
      int w = ty * 32 + tx;  // 0..255
      const int* mp = masks + w * 32;
      unsigned v = 0;
#pragma unroll
      for (int j = 0; j < 32; ++j) v |= (mp[j] ? 1u : 0u) << j;
      mbits[w] = v;
    }
    return;
  }
  const float* in = blockIdx.z == 0 ? Wq : (blockIdx.z == 1 ? Wk : Wv);
  __bf16* out = WtBase + (size_t)blockIdx.z * HID * HID;
  __shared__ __bf16 tile[32][33];
  int bx = blockIdx.x * 32, by = blockIdx.y * 32;
#pragma unroll
  for (int r = 0; r < 32; r += 8)
    tile[ty + r][tx] = (__bf16)in[(size_t)(by + ty + r) * HID + bx + tx];
  __syncthreads();
#pragma unroll
  for (int r = 0; r < 32; r += 8)
    out[(size_t)(bx + ty + r) * HID + by + tx] = tile[tx][ty + r];
}

// ---------- K+V projection (R21 form, passed; aux proven insensitive) ----------
__global__ __launch_bounds__(256, 5) void proj_kv(const float* __restrict__ toks,
                                                  const __bf16* __restrict__ WtK,
                                                  const float* __restrict__ bk,
                                                  const __bf16* __restrict__ WtV,
                                                  const float* __restrict__ bv,
                                                  __bf16* __restrict__ Kout,
                                                  __bf16* __restrict__ Vtout,
                                                  int head0, int hm) {
  __shared__ __align__(16) __bf16 ldsA[2][64 * ASTR];  // 2 x 9216 B
  int tid = threadIdx.x;
  int w = tid >> 6, lane = tid & 63, l16 = lane & 15, quad = lane >> 4;
  int m0 = blockIdx.x * 64;
  int hl = blockIdx.y, h = head0 + hl;
  int srow = tid >> 2, scg = tid & 3;
  const float* asrc = toks + (size_t)(m0 + srow) * HID + scg * 8;
  const __bf16* bKrow = WtK + (size_t)(h * 64 + w * 16 + l16) * HID + quad * 8;
  const __bf16* bVrow = WtV + (size_t)(h * 64 + w * 16 + l16) * HID + quad * 8;
  f32x4 zero = {0.f, 0.f, 0.f, 0.f};
  f32x4 aK[4], aV[4];
#pragma unroll
  for (int mt = 0; mt < 4; ++mt) { aK[mt] = zero; aV[mt] = zero; }

  *(bf16_8*)(&ldsA[0][srow * ASTR + scg * 8]) = cvt_a_frag(asrc);
  *(bf16_8*)(&ldsA[0][srow * ASTR + 32 + scg * 8]) = cvt_a_frag(asrc + 32);
  __syncthreads();

  const int NCH = HID / 64;  // 12
  for (int t = 0; t < NCH; ++t) {
    int b = t & 1;
    int kk = t * 64;
    bf16_8 areg0, areg1;
    if (t + 1 < NCH) {
      areg0 = cvt_a_frag(asrc + kk + 64);
      areg1 = cvt_a_frag(asrc + kk + 96);
    }
    bf16_8 bkf0 = *(const bf16_8*)(bKrow + kk);
    bf16_8 bkf1 = *(const bf16_8*)(bKrow + kk + 32);
    bf16_8 bvf0 = *(const bf16_8*)(bVrow + kk);
    bf16_8 bvf1 = *(const bf16_8*)(bVrow + kk + 32);
#pragma unroll
    for (int mt = 0; mt < 4; ++mt) {
      bf16_8 af0 = *(const bf16_8*)(&ldsA[b][(mt * 16 + l16) * ASTR + quad * 8]);
      bf16_8 af1 = *(const bf16_8*)(&ldsA[b][(mt * 16 + l16) * ASTR + 32 + quad * 8]);
      aK[mt] = mfma16x16x32(af0, bkf0, aK[mt]);
      aK[mt] = mfma16x16x32(af1, bkf1, aK[mt]);
      aV[mt] = mfma16x16x32(af0, bvf0, aV[mt]);
      aV[mt] = mfma16x16x32(af1, bvf1, aV[mt]);
    }
    if (t + 1 < NCH) {
      *(bf16_8*)(&ldsA[b ^ 1][srow * ASTR + scg * 8]) = areg0;
      *(bf16_8*)(&ldsA[b ^ 1][srow * ASTR + 32 + scg * 8]) = areg1;
      lds_barrier();
    }
  }

  int d = w * 16 + l16;
  float bnK = bk[h * 64 + d];
  float bnV = bv[h * 64 + d];
#pragma unroll
  for (int mt = 0; mt < 4; ++mt) {
#pragma unroll
    for (int r = 0; r < 4; ++r) {
      int m = m0 + mt * 16 + quad * 4 + r;
      int b = m >> 11;
      int s = m & (SEQ - 1);
      Kout[(((size_t)b * hm + hl) * SEQ + s) * HD + d] = (__bf16)(aK[mt][r] + bnK);
      Vtout[(((size_t)b * hm + hl) * HD + d) * SEQ + s] = (__bf16)(aV[mt][r] + bnV);
    }
  }
}

// ---------- fused Q-proj + flash attention: triple-buffer, 1 barrier/iter ----------
// Block 256 thr = 4 waves, each owning 32 q (q = q0b + w*32 + l32) of one
// (b,h). K/V triple buffer (buf b at L[b*8192]: K@+0, V@+4096); Q slab aliases
// buffer 2 (prologue-only). Per iter: vmcnt(4)+barrier -> issue own 4 DMAs for
// tile t+2 into buf((t+2)%3) [the buffer everyone finished reading last iter]
// -> body. 2-body DMA slack; ONE barrier/iter; loop VMEM = exactly 4 DMAs.
__global__ __launch_bounds__(256, 3) void attn_fused(const float* __restrict__ toks,
                                                     const __bf16* __restrict__ WtQ,
                                                     const float* __restrict__ bq,
                                                     const __bf16* __restrict__ Kbuf,
                                                     const __bf16* __restrict__ Vtbuf,
                                                     const unsigned* __restrict__ mbits,
                                                     float* __restrict__ out,
                                                     int head0, int hm) {
  __shared__ __align__(16) __bf16 L[24576];  // 3 x (K 4096 + V 4096); Q aliases buf2
  int tid = threadIdx.x;
  int w = tid >> 6, lane = tid & 63;
  int l16 = lane & 15, quad = lane >> 4, l32 = lane & 31, hi = lane >> 5;

  // XCD-locality remap (T1, proven)
  int nwg = gridDim.x * gridDim.y * gridDim.z;           // 768 (A) / 64 (B)
  int hwf = blockIdx.x + gridDim.x * (blockIdx.y + gridDim.y * blockIdx.z);
  int lg = (hwf & 7) * (nwg >> 3) + (hwf >> 3);
  int q0b = (lg & (gridDim.x - 1)) * 128;                // gridDim.x = 16
  int grp = lg / gridDim.x;
  int hl = grp % hm, bz = grp / hm;
  int h = head0 + hl;

  f32x4 zero = {0.f, 0.f, 0.f, 0.f};
  const __bf16* Kb = Kbuf + ((size_t)bz * hm + hl) * SEQ * HD;
  const __bf16* Vb = Vtbuf + ((size_t)bz * hm + hl) * HD * SEQ;

  // --- mask bits FIRST (oldest VMEM; retires before DMAs by in-order rule) ---
  unsigned mask_all = mbits[bz * 64 + lane];

  // --- DMA lane constants (R21-verified): linear dest, pre-swizzled source ---
  int drow = lane >> 3, dch = lane & 7;
  int dswz = (dch ^ drow) * 8;  // row&7 == drow for every 8-row DMA group
  const __bf16* kSrc = Kb + (size_t)drow * HD + dswz;
  const __bf16* vSrc = Vb + (size_t)drow * SEQ + dswz;
  int gk0 = 2 * w, gk1 = 2 * w + 1;  // this wave's K/V DMA groups

  // --- prologue DMAs: tiles 0 -> buf0, 1 -> buf1 (hidden under Q-proj) ---
  gll16(kSrc + (size_t)(gk0 * 8) * HD, &L[0 + gk0 * 512]);
  gll16(kSrc + (size_t)(gk1 * 8) * HD, &L[0 + gk1 * 512]);
  gll16(vSrc + (size_t)(gk0 * 8) * SEQ + 0, &L[4096 + gk0 * 512]);
  gll16(vSrc + (size_t)(gk1 * 8) * SEQ + 0, &L[4096 + gk1 * 512]);
  gll16(kSrc + (size_t)(KVB + gk0 * 8) * HD, &L[8192 + gk0 * 512]);
  gll16(kSrc + (size_t)(KVB + gk1 * 8) * HD, &L[8192 + gk1 * 512]);
  gll16(vSrc + (size_t)(gk0 * 8) * SEQ + KVB, &L[12288 + gk0 * 512]);
  gll16(vSrc + (size_t)(gk1 * 8) * SEQ + KVB, &L[12288 + gk1 * 512]);

  // --- Q projection: wave w -> rows q0b + w*32 .. +32 into slab (aliases buf2) ---
  __bf16* Qs = &L[16384 + (w * 32) * STRQ];
#pragma unroll
  for (int qs = 0; qs < 2; ++qs) {
    const float* arow =
        toks + ((size_t)bz * SEQ + q0b + w * 32 + qs * 16 + l16) * HID + quad * 8;
    const __bf16* brow = WtQ + (size_t)(h * 64 + l16) * HID + quad * 8;
    f32x4 qa[4] = {zero, zero, zero, zero};
    for (int kk = 0; kk < HID; kk += 32) {
      bf16_8 a = cvt_a_frag(arow + kk);
#pragma unroll
      for (int t = 0; t < 4; ++t)
        qa[t] = mfma16x16x32(a, *(const bf16_8*)(brow + (size_t)t * 16 * HID + kk), qa[t]);
    }
#pragma unroll
    for (int t = 0; t < 4; ++t) {
      float bn = bq[h * 64 + t * 16 + l16];
#pragma unroll
      for (int r = 0; r < 4; ++r)
        Qs[(qs * 16 + quad * 4 + r) * STRQ + t * 16 + l16] = (__bf16)(qa[t][r] + bn);
    }
  }
  lds_flush();  // own-wave Q writes visible (slab is wave-private)

  // Q B-frags: lane holds Q[q = w*32 + l32][d = c*16 + hi*8 + j]  (R18-verified)
  bf16_8 qf0 = cat2(&Qs[l32 * STRQ + 0 * 16 + hi * 8]);
  bf16_8 qf1 = cat2(&Qs[l32 * STRQ + 1 * 16 + hi * 8]);
  bf16_8 qf2 = cat2(&Qs[l32 * STRQ + 2 * 16 + hi * 8]);
  bf16_8 qf3 = cat2(&Qs[l32 * STRQ + 3 * 16 + hi * 8]);
  unsigned qw = (unsigned)__builtin_amdgcn_readlane((int)mask_all, (q0b >> 5) + w);
  bool act = (qw >> l32) & 1u;
  float smq = act ? SCALE2 : 0.0f;
  lds_flush();  // Q reads retired before buf2's first DMA can land (post-barrier)

  // read-side swizzled chunk offsets (R21-verified)
  int xkh = (l32 >> 1) & 3;
  int e0 = (hi ^ (l32 & 1)) << 3;
  int o0 = ((0 ^ xkh) << 4) + e0;
  int o1 = ((1 ^ xkh) << 4) + e0;
  int o2 = ((2 ^ xkh) << 4) + e0;
  int o3 = ((3 ^ xkh) << 4) + e0;

  float lsum = 0.f;
  f32x16 acc0, acc1;  // [dhalf], named
#pragma unroll
  for (int i = 0; i < 16; ++i) { acc0[i] = 0.f; acc1[i] = 0.f; }

  int bc = 0;  // buffer holding tile t (uniform; rotates 0,1,2)
  for (int t = 0; t < NKT; ++t) {
    // tile t's own 4 DMAs landed (t+1's stay in flight); barrier additionally
    // certifies every wave finished reading buf((t+2)%3) during iter t-1.
    __asm__ volatile("s_waitcnt vmcnt(4)\n\ts_barrier" ::: "memory");
    // issue own 4 DMAs for tile t+2 into the just-freed buffer (2-body slack)
    int bn = bc + 2; if (bn >= 3) bn -= 3;
    int dstB = bn * 8192;
    int jd = ((t + 2) & (NKT - 1)) * KVB;  // wrap: garbage reload, never read
    gll16(kSrc + (size_t)(jd + gk0 * 8) * HD, &L[dstB + gk0 * 512]);
    gll16(kSrc + (size_t)(jd + gk1 * 8) * HD, &L[dstB + gk1 * 512]);
    gll16(vSrc + (size_t)(gk0 * 8) * SEQ + jd, &L[dstB + 4096 + gk0 * 512]);
    gll16(vSrc + (size_t)(gk1 * 8) * SEQ + jd, &L[dstB + 4096 + gk1 * 512]);

    const __bf16* LK = L + bc * 8192;
    const __bf16* LV = L + bc * 8192 + 4096;
    unsigned m0w = (unsigned)__builtin_amdgcn_readlane((int)mask_all, 2 * t);
    unsigned m1w = (unsigned)__builtin_amdgcn_readlane((int)mask_all, 2 * t + 1);
    unsigned mh0 = m0w >> (hi * 4);
    unsigned mh1 = m1w >> (hi * 4);
#pragma unroll
    for (int s = 0; s < 2; ++s) {
      unsigned mhs = s ? mh1 : mh0;
      int krow = (s * 32 + l32) * 64;
      bf16_8 kf0 = *(const bf16_8*)(LK + krow + o0);
      bf16_8 kf1 = *(const bf16_8*)(LK + krow + o1);
      bf16_8 kf2 = *(const bf16_8*)(LK + krow + o2);
      bf16_8 kf3 = *(const bf16_8*)(LK + krow + o3);
      bf16_8 vf00 = *(const bf16_8*)(LV + (l32)*64 + (s ? o2 : o0));
      bf16_8 vf01 = *(const bf16_8*)(LV + (l32)*64 + (s ? o3 : o1));
      bf16_8 vf10 = *(const bf16_8*)(LV + (32 + l32) * 64 + (s ? o2 : o0));
      bf16_8 vf11 = *(const bf16_8*)(LV + (32 + l32) * 64 + (s ? o3 : o1));
      // --- QK^T: S^T[key = s*32 + (r&3)+8*(r>>2)+4*hi][q = w*32 + l32] ---
      f32x16 st;
#pragma unroll
      for (int i = 0; i < 16; ++i) st[i] = 0.f;
      st = mfma32x32x16(kf0, qf0, st);
      st = mfma32x32x16(kf1, qf1, st);
      st = mfma32x32x16(kf2, qf2, st);
      st = mfma32x32x16(kf3, qf3, st);
      // --- softmax numerators via bitmask (R21-verified) ---
      unsigned gate = act ? ~mhs : 0u;
      unsigned wds[8];
      float ls = 0.f;
#pragma unroll
      for (int g = 0; g < 4; ++g) {
        float ck0 = (gate & (1u << (8 * g + 0))) ? NEGBIG2 : 0.0f;
        float ck1 = (gate & (1u << (8 * g + 1))) ? NEGBIG2 : 0.0f;
        float ck2 = (gate & (1u << (8 * g + 2))) ? NEGBIG2 : 0.0f;
        float ck3 = (gate & (1u << (8 * g + 3))) ? NEGBIG2 : 0.0f;
        float p0 = fast_exp2(fmaf(st[g * 4 + 0], smq, ck0));
        float p1 = fast_exp2(fmaf(st[g * 4 + 1], smq, ck1));
        float p2 = fast_exp2(fmaf(st[g * 4 + 2], smq, ck2));
        float p3 = fast_exp2(fmaf(st[g * 4 + 3], smq, ck3));
        ls += (p0 + p1) + (p2 + p3);
        wds[g * 2] = pkbf(p0, p1);
        wds[g * 2 + 1] = pkbf(p2, p3);
      }
      lsum += ls;
      // --- in-register P -> PV A-frags (R21-verified) ---
      pl32swap(wds[0], wds[2]);
      pl32swap(wds[1], wds[3]);
      pl32swap(wds[4], wds[6]);
      pl32swap(wds[5], wds[7]);
      u32x4 pd0 = {wds[0], wds[1], wds[2], wds[3]};
      u32x4 pd1 = {wds[4], wds[5], wds[6], wds[7]};
      bf16_8 pa0 = __builtin_bit_cast(bf16_8, pd0);  // P[q][keys s*32+0..15]
      bf16_8 pa1 = __builtin_bit_cast(bf16_8, pd1);  // P[q][keys s*32+16..31]
      acc0 = mfma32x32x16(pa1, vf01, mfma32x32x16(pa0, vf00, acc0));
      acc1 = mfma32x32x16(pa1, vf11, mfma32x32x16(pa0, vf10, acc1));
    }
    bc = bc + 1; if (bc >= 3) bc -= 3;
  }
  __asm__ volatile("s_waitcnt vmcnt(0)" ::: "memory");  // drain tail DMAs

  // --- normalize + store (epilogue-only cross-lane; R21-verified map) ---
  float v = lsum;
  v += __shfl_xor(v, 32);
  float linv = 1.0f / v;  // valid for q = q0b + w*32 + l32
#pragma unroll
  for (int r = 0; r < 16; ++r) {
    int row = (r & 3) + 8 * (r >> 2) + 4 * hi;
    float sc = __shfl(linv, row);
    size_t orow = (size_t)bz * SEQ + q0b + w * 32 + row;
    out[orow * HID + h * HD + l32] = acc0[r] * sc;
    out[orow * HID + h * HD + 32 + l32] = acc1[r] * sc;
  }
}

extern "C" void kernel_launch(void* const* d_in, const int* in_sizes, int n_in,
                              void* d_out, int out_size, void* d_ws, size_t ws_size,
                              hipStream_t stream) {
  (void)in_sizes; (void)n_in; (void)out_size;
  const float* toks = (const float*)d_in[0];
  const int* masks = (const int*)d_in[1];
  const float* Wq = (const float*)d_in[2];
  const float* bq = (const float*)d_in[3];
  const float* Wk = (const float*)d_in[4];
  const float* bk = (const float*)d_in[5];
  const float* Wv = (const float*)d_in[6];
  const float* bv = (const float*)d_in[7];
  char* ws = (char*)d_ws;
  const size_t MB_B = 1024;  // unsigned[256] mask bit-words
  const size_t WT_B = (size_t)HID * HID * 2;
  const size_t KV_FULL_B = (size_t)BATCH * NHEADS * SEQ * HD * 2;
  const size_t KV_HEAD_B = (size_t)BATCH * SEQ * HD * 2;
  const size_t TIER_A_NEED = MB_B + 3 * WT_B + 2 * KV_FULL_B;  // ~28.7 MB
  unsigned* mbits = (unsigned*)(ws);
  __bf16* WtQ = (__bf16*)(ws + MB_B + 0 * WT_B);
  __bf16* WtK = (__bf16*)(ws + MB_B + 1 * WT_B);
  __bf16* WtV = (__bf16*)(ws + MB_B + 2 * WT_B);
  float* outp = (float*)d_out;

  dim3 tgrid(HID / 32, HID / 32, 4), tblk(32, 8);
  transpose768x3<<<tgrid, tblk, 0, stream>>>(Wq, Wk, Wv, WtQ, masks, mbits);

  if (ws_size >= TIER_A_NEED) {
    __bf16* Kf = (__bf16*)(ws + MB_B + 3 * WT_B);
    __bf16* Vtf = (__bf16*)(ws + MB_B + 3 * WT_B + KV_FULL_B);
    dim3 pgrid(BATCH * SEQ / 64, NHEADS);
    proj_kv<<<pgrid, 256, 0, stream>>>(toks, WtK, bk, WtV, bv, Kf, Vtf, 0, NHEADS);
    dim3 agrid(SEQ / 128, NHEADS, BATCH);
    attn_fused<<<agrid, 256, 0, stream>>>(toks, WtQ, bq, Kf, Vtf, mbits, outp, 0, NHEADS);
  } else {
    __bf16* Kh = (__bf16*)(ws + MB_B + 3 * WT_B);
    __bf16* Vth = (__bf16*)(ws + MB_B + 3 * WT_B + KV_HEAD_B);
    dim3 pgrid(BATCH * SEQ / 64, 1);
    dim3 agrid(SEQ / 128, 1, BATCH);
    for (int h = 0; h < NHEADS; ++h) {
      proj_kv<<<pgrid, 256, 0, stream>>>(toks, WtK, bk, WtV, bv, Kh, Vth, h, 1);
      attn_fused<<<agrid, 256, 0, stream>>>(toks, WtQ, bq, Kh, Vth, mbits, outp, h, 1);
    }
  }
}